// Round 3
// baseline (367.545 us; speedup 1.0000x reference)
//
#include <hip/hip_runtime.h>
#include <hip/hip_bf16.h>
#include <math.h>

#define N_NODES 50000
#define E_EDGES 262144
#define D_FEAT  128
#define H_HID   256
#define NEXP    4

typedef __attribute__((ext_vector_type(8))) short  short8;
typedef __attribute__((ext_vector_type(4))) float  floatx4;

// ws layout:
//   [0..15]                      float probsum[4]
//   [16..31]                     unsigned count[4]
//   [32 .. 32+16*E)              int lists[4][E]
//   [+4*E)                       float pval[E]
//   [+512K)                      ushort w1b[262144]  (bf16, B-fragment-linear)
#define W1B_OFF0 0
#define W1B_OFF1 65536      // 256*256
#define W1B_OFF2 98304      // +128*256
#define W1B_OFF3 131072     // +128*256

__device__ __forceinline__ unsigned short f2bf(float f) {
    __hip_bfloat16 h = __float2bfloat16(f);       // RNE
    return *reinterpret_cast<unsigned short*>(&h);
}

// ---------------------------------------------------------------------------
// Phase 0: convert the four W1 matrices to bf16 in B-fragment-linear layout:
//   w1b[exoff + ((k>>3)*256 + n)*8 + (k&7)] = bf16(w1[k*256+n])
// ---------------------------------------------------------------------------
__global__ __launch_bounds__(256) void conv_kernel(
    const float* __restrict__ cw1, const float* __restrict__ dw1,
    const float* __restrict__ mw1, const float* __restrict__ aw1,
    unsigned short* __restrict__ w1b)
{
    int r = blockIdx.x;          // 0..1023 global K row
    int n = threadIdx.x;         // 0..255
    const float* src; int k, off;
    if (r < 256)      { src = cw1; k = r;       off = W1B_OFF0; }
    else if (r < 384) { src = dw1; k = r - 256; off = W1B_OFF1; }
    else if (r < 512) { src = mw1; k = r - 384; off = W1B_OFF2; }
    else              { src = aw1; k = r - 512; off = W1B_OFF3; }
    w1b[off + (((k >> 3) * 256 + n) << 3) + (k & 7)] = f2bf(src[k * 256 + n]);
}

// ---------------------------------------------------------------------------
// Phase 1: gate. Wave-cooperative: lane l owns features d = 2l, 2l+1 with its
// 32 gate_w values pre-converted to fp64 in REGISTERS (no per-edge w loads).
// Per edge: coalesced float2 z reads, 32 dfma, 6-step fp64 butterfly; logits
// for edge i end up in lane i. Tail (softmax fp64, fp32-prob argmax,
// ballot compaction) is identical to the previously-passing version.
// ---------------------------------------------------------------------------
__global__ __launch_bounds__(256) void gate_kernel(
    const float* __restrict__ z, const int* __restrict__ u, const int* __restrict__ v,
    const float* __restrict__ gw, const float* __restrict__ gb,
    float* __restrict__ probsum, unsigned* __restrict__ gcount,
    int* __restrict__ lists, float* __restrict__ pval)
{
    int tid  = threadIdx.x;
    int lane = tid & 63;
    int wave = tid >> 6;
    int base_e = blockIdx.x * 256 + wave * 64;

    // coalesced batch load of this wave's 64 edge endpoints
    int ul = u[base_e + lane];
    int vl = v[base_e + lane];

    // register weights: dw[featblock][d-sub][out], fp64
    double dw[4][2][4];
    #pragma unroll
    for (int fb = 0; fb < 4; ++fb) {
        float4 w0 = *(const float4*)(gw + 4 * (fb * 128 + 2 * lane));
        float4 w1 = *(const float4*)(gw + 4 * (fb * 128 + 2 * lane + 1));
        dw[fb][0][0] = (double)w0.x; dw[fb][0][1] = (double)w0.y;
        dw[fb][0][2] = (double)w0.z; dw[fb][0][3] = (double)w0.w;
        dw[fb][1][0] = (double)w1.x; dw[fb][1][1] = (double)w1.y;
        dw[fb][1][2] = (double)w1.z; dw[fb][1][3] = (double)w1.w;
    }

    double L0 = 0.0, L1 = 0.0, L2 = 0.0, L3 = 0.0;   // saved logits (lane i <- edge i)

    for (int i = 0; i < 64; ++i) {
        int ue = __shfl(ul, i);
        int ve = __shfl(vl, i);
        float2 a2 = *(const float2*)(z + (long)ue * D_FEAT + 2 * lane);
        float2 b2 = *(const float2*)(z + (long)ve * D_FEAT + 2 * lane);

        double p0 = 0.0, p1 = 0.0, p2 = 0.0, p3 = 0.0;
        // d0 = 2*lane  (features computed in fp32 like numpy, then widened)
        {
            float adf = fabsf(a2.x - b2.x);
            float mf  = a2.x * b2.x;
            double a = (double)a2.x, b = (double)b2.x, ad = (double)adf, m = (double)mf;
            p0 += a * dw[0][0][0] + b * dw[1][0][0] + ad * dw[2][0][0] + m * dw[3][0][0];
            p1 += a * dw[0][0][1] + b * dw[1][0][1] + ad * dw[2][0][1] + m * dw[3][0][1];
            p2 += a * dw[0][0][2] + b * dw[1][0][2] + ad * dw[2][0][2] + m * dw[3][0][2];
            p3 += a * dw[0][0][3] + b * dw[1][0][3] + ad * dw[2][0][3] + m * dw[3][0][3];
        }
        // d1 = 2*lane+1
        {
            float adf = fabsf(a2.y - b2.y);
            float mf  = a2.y * b2.y;
            double a = (double)a2.y, b = (double)b2.y, ad = (double)adf, m = (double)mf;
            p0 += a * dw[0][1][0] + b * dw[1][1][0] + ad * dw[2][1][0] + m * dw[3][1][0];
            p1 += a * dw[0][1][1] + b * dw[1][1][1] + ad * dw[2][1][1] + m * dw[3][1][1];
            p2 += a * dw[0][1][2] + b * dw[1][1][2] + ad * dw[2][1][2] + m * dw[3][1][2];
            p3 += a * dw[0][1][3] + b * dw[1][1][3] + ad * dw[2][1][3] + m * dw[3][1][3];
        }
        // butterfly sum across 64 lanes
        #pragma unroll
        for (int mk = 1; mk < 64; mk <<= 1) {
            p0 += __shfl_xor(p0, mk);
            p1 += __shfl_xor(p1, mk);
            p2 += __shfl_xor(p2, mk);
            p3 += __shfl_xor(p3, mk);
        }
        if (lane == i) { L0 = p0; L1 = p1; L2 = p2; L3 = p3; }
    }

    // ---- tail: thread tid owns edge blockIdx*256 + tid (== base_e + lane) ----
    int e = blockIdx.x * 256 + tid;

    double l0 = L0 + (double)gb[0], l1 = L1 + (double)gb[1];
    double l2 = L2 + (double)gb[2], l3 = L3 + (double)gb[3];

    double mx = fmax(fmax(l0, l1), fmax(l2, l3));
    double e0 = exp(l0 - mx), e1 = exp(l1 - mx), e2 = exp(l2 - mx), e3 = exp(l3 - mx);
    double s  = e0 + e1 + e2 + e3;
    float p[4];
    p[0] = (float)(e0 / s); p[1] = (float)(e1 / s);
    p[2] = (float)(e2 / s); p[3] = (float)(e3 / s);

    int   sel  = 0;
    float best = p[0];
    #pragma unroll
    for (int k = 1; k < 4; ++k) {            // strict > keeps first index on ties
        if (p[k] > best) { best = p[k]; sel = k; }
    }

    __shared__ float s_ps[4];
    __shared__ int   s_cnt[4];
    __shared__ int   s_base[4];
    if (tid < 4) { s_ps[tid] = 0.0f; s_cnt[tid] = 0; }
    __syncthreads();

    float q0 = p[0], q1 = p[1], q2 = p[2], q3 = p[3];
    #pragma unroll
    for (int off = 32; off > 0; off >>= 1) {
        q0 += __shfl_down(q0, off);
        q1 += __shfl_down(q1, off);
        q2 += __shfl_down(q2, off);
        q3 += __shfl_down(q3, off);
    }
    if (lane == 0) {
        atomicAdd(&s_ps[0], q0); atomicAdd(&s_ps[1], q1);
        atomicAdd(&s_ps[2], q2); atomicAdd(&s_ps[3], q3);
    }

    unsigned long long lt = (lane == 0) ? 0ull : ((~0ull) >> (64 - lane));
    int mywb = 0, myrank = 0;
    #pragma unroll
    for (int k = 0; k < 4; ++k) {
        unsigned long long mask = __ballot(sel == k);
        if (mask) {
            int leader = (int)__ffsll((unsigned long long)mask) - 1;
            int wb = 0;
            if (lane == leader) wb = atomicAdd(&s_cnt[k], (int)__popcll(mask));
            wb = __shfl(wb, leader);
            if (sel == k) { mywb = wb; myrank = (int)__popcll(mask & lt); }
        }
    }
    __syncthreads();

    if (tid < 4) {
        s_base[tid] = (int)atomicAdd(&gcount[tid], (unsigned)s_cnt[tid]);
        atomicAdd(&probsum[tid], s_ps[tid]);
    }
    __syncthreads();

    int pos = s_base[sel] + mywb + myrank;
    lists[sel * E_EDGES + pos] = e;
    pval[e] = best;
}

// ---------------------------------------------------------------------------
// Phase 2: selected-expert MLP via bf16 MFMA. Tile = 64 edges x 256 hidden.
// Block = 4 waves; wave w owns hidden cols [w*64, +64): 4 M-tiles x 4 N-tiles.
// ---------------------------------------------------------------------------
#define FPAD 40   // row stride (elems): 80B rows keep b128 16B-aligned

__device__ __forceinline__ float4 feat4(int ex, const float* zu, const float* zv, int fg) {
    if (ex == 0) {
        return (fg < 128) ? *(const float4*)(zu + fg) : *(const float4*)(zv + fg - 128);
    } else if (ex == 1) {
        float4 a = *(const float4*)(zu + fg);
        float4 b = *(const float4*)(zv + fg);
        return make_float4(fabsf(a.x - b.x), fabsf(a.y - b.y), fabsf(a.z - b.z), fabsf(a.w - b.w));
    } else if (ex == 2) {
        float4 a = *(const float4*)(zu + fg);
        float4 b = *(const float4*)(zv + fg);
        return make_float4(a.x * b.x, a.y * b.y, a.z * b.z, a.w * b.w);
    } else {
        if (fg < 128) return *(const float4*)(zu + fg);
        if (fg < 256) return *(const float4*)(zv + fg - 128);
        if (fg < 384) {
            float4 a = *(const float4*)(zu + fg - 256);
            float4 b = *(const float4*)(zv + fg - 256);
            return make_float4(fabsf(a.x - b.x), fabsf(a.y - b.y), fabsf(a.z - b.z), fabsf(a.w - b.w));
        }
        float4 a = *(const float4*)(zu + fg - 384);
        float4 b = *(const float4*)(zv + fg - 384);
        return make_float4(a.x * b.x, a.y * b.y, a.z * b.z, a.w * b.w);
    }
}

__global__ __launch_bounds__(256) void expert_kernel(
    const float* __restrict__ z, const int* __restrict__ u, const int* __restrict__ v,
    const unsigned short* __restrict__ w1b,
    const float* __restrict__ cb1, const float* __restrict__ cw2, const float* __restrict__ cb2,
    const float* __restrict__ db1, const float* __restrict__ dw2, const float* __restrict__ db2,
    const float* __restrict__ mb1, const float* __restrict__ mw2, const float* __restrict__ mb2,
    const float* __restrict__ ab1, const float* __restrict__ aw2, const float* __restrict__ ab2,
    const unsigned* __restrict__ gcount, const int* __restrict__ lists,
    const float* __restrict__ pval, float* __restrict__ out)
{
    int ex = blockIdx.y;
    const float *b1, *w2, *b2;
    int F, w1off;
    if (ex == 0)      { b1 = cb1; w2 = cw2; b2 = cb2; F = 256; w1off = W1B_OFF0; }
    else if (ex == 1) { b1 = db1; w2 = dw2; b2 = db2; F = 128; w1off = W1B_OFF1; }
    else if (ex == 2) { b1 = mb1; w2 = mw2; b2 = mb2; F = 128; w1off = W1B_OFF2; }
    else              { b1 = ab1; w2 = aw2; b2 = ab2; F = 512; w1off = W1B_OFF3; }

    unsigned cnt  = gcount[ex];
    unsigned tile = blockIdx.x * 64u;
    if (tile >= cnt) return;
    int nm = (int)min(64u, cnt - tile);

    __shared__ unsigned short featA[64 * FPAD];
    __shared__ int   s_e[64], s_u[64], s_v[64];
    __shared__ float s_pv[64];
    __shared__ float red[4][64];

    int tid  = threadIdx.x;
    int wave = tid >> 6;
    int lane = tid & 63;
    int colA = lane & 15;
    int quad = lane >> 4;

    if (tid < 64) {
        int m = tid;
        int src = (m < nm) ? (int)(tile + m) : (int)tile;   // clamp tail
        int e = lists[ex * E_EDGES + src];
        s_e[m] = e; s_u[m] = u[e]; s_v[m] = v[e]; s_pv[m] = pval[e];
    }
    __syncthreads();

    const short8* wB = (const short8*)(w1b + w1off);

    floatx4 acc[4][4];
    #pragma unroll
    for (int t = 0; t < 4; ++t)
        #pragma unroll
        for (int j = 0; j < 4; ++j)
            acc[t][j] = (floatx4)(0.0f);

    // feature-build map: thread -> (edge fm, 8 consecutive features fk..fk+7)
    int fm = tid >> 2;
    int fk = (tid & 3) << 3;

    for (int f0 = 0; f0 < F; f0 += 32) {
        // B-fragment loads first (no LDS dependence)
        int g  = (f0 >> 3) + quad;
        int nb = wave * 64 + colA;
        short8 bf0 = wB[g * 256 + nb +  0];
        short8 bf1 = wB[g * 256 + nb + 16];
        short8 bf2 = wB[g * 256 + nb + 32];
        short8 bf3 = wB[g * 256 + nb + 48];

        if (f0 > 0) __syncthreads();   // previous chunk's reads done
        {
            int fg = f0 + fk;
            const float* zu = z + (long)s_u[fm] * D_FEAT;
            const float* zv = z + (long)s_v[fm] * D_FEAT;
            float4 v0 = feat4(ex, zu, zv, fg);
            float4 v1 = feat4(ex, zu, zv, fg + 4);
            short8 pk;
            pk[0] = (short)f2bf(v0.x); pk[1] = (short)f2bf(v0.y);
            pk[2] = (short)f2bf(v0.z); pk[3] = (short)f2bf(v0.w);
            pk[4] = (short)f2bf(v1.x); pk[5] = (short)f2bf(v1.y);
            pk[6] = (short)f2bf(v1.z); pk[7] = (short)f2bf(v1.w);
            *(short8*)(&featA[fm * FPAD + fk]) = pk;
        }
        __syncthreads();

        short8 a0 = *(const short8*)(&featA[(colA +  0) * FPAD + quad * 8]);
        short8 a1 = *(const short8*)(&featA[(colA + 16) * FPAD + quad * 8]);
        short8 a2 = *(const short8*)(&featA[(colA + 32) * FPAD + quad * 8]);
        short8 a3 = *(const short8*)(&featA[(colA + 48) * FPAD + quad * 8]);

        acc[0][0] = __builtin_amdgcn_mfma_f32_16x16x32_bf16(a0, bf0, acc[0][0], 0, 0, 0);
        acc[1][0] = __builtin_amdgcn_mfma_f32_16x16x32_bf16(a1, bf0, acc[1][0], 0, 0, 0);
        acc[2][0] = __builtin_amdgcn_mfma_f32_16x16x32_bf16(a2, bf0, acc[2][0], 0, 0, 0);
        acc[3][0] = __builtin_amdgcn_mfma_f32_16x16x32_bf16(a3, bf0, acc[3][0], 0, 0, 0);
        acc[0][1] = __builtin_amdgcn_mfma_f32_16x16x32_bf16(a0, bf1, acc[0][1], 0, 0, 0);
        acc[1][1] = __builtin_amdgcn_mfma_f32_16x16x32_bf16(a1, bf1, acc[1][1], 0, 0, 0);
        acc[2][1] = __builtin_amdgcn_mfma_f32_16x16x32_bf16(a2, bf1, acc[2][1], 0, 0, 0);
        acc[3][1] = __builtin_amdgcn_mfma_f32_16x16x32_bf16(a3, bf1, acc[3][1], 0, 0, 0);
        acc[0][2] = __builtin_amdgcn_mfma_f32_16x16x32_bf16(a0, bf2, acc[0][2], 0, 0, 0);
        acc[1][2] = __builtin_amdgcn_mfma_f32_16x16x32_bf16(a1, bf2, acc[1][2], 0, 0, 0);
        acc[2][2] = __builtin_amdgcn_mfma_f32_16x16x32_bf16(a2, bf2, acc[2][2], 0, 0, 0);
        acc[3][2] = __builtin_amdgcn_mfma_f32_16x16x32_bf16(a3, bf2, acc[3][2], 0, 0, 0);
        acc[0][3] = __builtin_amdgcn_mfma_f32_16x16x32_bf16(a0, bf3, acc[0][3], 0, 0, 0);
        acc[1][3] = __builtin_amdgcn_mfma_f32_16x16x32_bf16(a1, bf3, acc[1][3], 0, 0, 0);
        acc[2][3] = __builtin_amdgcn_mfma_f32_16x16x32_bf16(a2, bf3, acc[2][3], 0, 0, 0);
        acc[3][3] = __builtin_amdgcn_mfma_f32_16x16x32_bf16(a3, bf3, acc[3][3], 0, 0, 0);
        __syncthreads();
    }

    // epilogue: hidden = relu(acc + b1[h]); per-edge sum of hidden*w2[h]
    float b1v[4], w2v[4];
    #pragma unroll
    for (int j = 0; j < 4; ++j) {
        int h = wave * 64 + j * 16 + colA;
        b1v[j] = b1[h];
        w2v[j] = w2[h];
    }

    #pragma unroll
    for (int t = 0; t < 4; ++t) {
        #pragma unroll
        for (int r = 0; r < 4; ++r) {
            float s = 0.0f;
            #pragma unroll
            for (int j = 0; j < 4; ++j) {
                float h = acc[t][j][r] + b1v[j];
                s += fmaxf(h, 0.0f) * w2v[j];
            }
            s += __shfl_xor(s, 1);
            s += __shfl_xor(s, 2);
            s += __shfl_xor(s, 4);
            s += __shfl_xor(s, 8);
            if (colA == 0) {
                int m = 16 * t + quad * 4 + r;
                red[wave][m] = s;
            }
        }
    }
    __syncthreads();

    if (tid < 64) {
        int m = tid;
        if (m < nm) {
            float sc = red[0][m] + red[1][m] + red[2][m] + red[3][m] + b2[0];
            out[s_e[m]] = s_pv[m] * sc;
        }
    }
}

// ---------------------------------------------------------------------------
// Phase 3: aux loss
// ---------------------------------------------------------------------------
__global__ void aux_kernel(const float* __restrict__ probsum, float* __restrict__ out)
{
    if (threadIdx.x == 0 && blockIdx.x == 0) {
        float a = 0.0f;
        #pragma unroll
        for (int k = 0; k < 4; ++k) {
            float mean = probsum[k] * (1.0f / (float)E_EDGES);
            a += mean * mean;
        }
        out[E_EDGES] = a * (float)NEXP;
    }
}

extern "C" void kernel_launch(void* const* d_in, const int* in_sizes, int n_in,
                              void* d_out, int out_size, void* d_ws, size_t ws_size,
                              hipStream_t stream)
{
    const float* z   = (const float*)d_in[0];
    const int*   u   = (const int*)d_in[1];
    const int*   v   = (const int*)d_in[2];
    const float* gw  = (const float*)d_in[3];
    const float* gb  = (const float*)d_in[4];
    const float* cw1 = (const float*)d_in[5];
    const float* cb1 = (const float*)d_in[6];
    const float* cw2 = (const float*)d_in[7];
    const float* cb2 = (const float*)d_in[8];
    const float* dw1 = (const float*)d_in[9];
    const float* db1 = (const float*)d_in[10];
    const float* dw2 = (const float*)d_in[11];
    const float* db2 = (const float*)d_in[12];
    const float* mw1 = (const float*)d_in[13];
    const float* mb1 = (const float*)d_in[14];
    const float* mw2 = (const float*)d_in[15];
    const float* mb2 = (const float*)d_in[16];
    const float* aw1 = (const float*)d_in[17];
    const float* ab1 = (const float*)d_in[18];
    const float* aw2 = (const float*)d_in[19];
    const float* ab2 = (const float*)d_in[20];

    float* out = (float*)d_out;
    char*  ws  = (char*)d_ws;

    float*          probsum = (float*)ws;
    unsigned*       gcount  = (unsigned*)(ws + 16);
    int*            lists   = (int*)(ws + 32);
    float*          pval    = (float*)(ws + 32 + 16ll * E_EDGES);
    unsigned short* w1b     = (unsigned short*)(ws + 32 + 20ll * E_EDGES);

    hipMemsetAsync(d_ws, 0, 32, stream);

    conv_kernel<<<1024, 256, 0, stream>>>(cw1, dw1, mw1, aw1, w1b);

    gate_kernel<<<E_EDGES / 256, 256, 0, stream>>>(z, u, v, gw, gb,
                                                   probsum, gcount, lists, pval);

    aux_kernel<<<1, 64, 0, stream>>>(probsum, out);

    dim3 g2(E_EDGES / 64, 4);
    expert_kernel<<<g2, 256, 0, stream>>>(z, u, v, w1b,
                                          cb1, cw2, cb2,
                                          db1, dw2, db2,
                                          mb1, mw2, mb2,
                                          ab1, aw2, ab2,
                                          gcount, lists, pval, out);
}

// Round 4
// 365.103 us; speedup vs baseline: 1.0067x; 1.0067x over previous
//
#include <hip/hip_runtime.h>
#include <hip/hip_bf16.h>
#include <math.h>

#define N_NODES 50000
#define E_EDGES 262144
#define D_FEAT  128
#define H_HID   256
#define NEXP    4

typedef __attribute__((ext_vector_type(8))) short  short8;
typedef __attribute__((ext_vector_type(4))) float  floatx4;

// ws layout:
//   [0..15]                       float probsum[4]
//   [16..31]                      unsigned count[4]
//   [32 .. 32+16*E)               int lists[4][E]
//   [+4*E)                        float pval[E]
//   [+512K)                       ushort w1b[262144]  (bf16, B-fragment-linear)
//   [+16K)                        double gwd[128*16]  (gate_w fp64, per-d packed)
#define W1B_OFF0 0
#define W1B_OFF1 65536      // 256*256
#define W1B_OFF2 98304      // +128*256
#define W1B_OFF3 131072     // +128*256

__device__ __forceinline__ unsigned short f2bf(float f) {
    __hip_bfloat16 h = __float2bfloat16(f);       // RNE
    return *reinterpret_cast<unsigned short*>(&h);
}

// ---------------------------------------------------------------------------
// Phase 0a: W1 matrices -> bf16 B-fragment-linear layout.
// ---------------------------------------------------------------------------
__global__ __launch_bounds__(256) void conv_kernel(
    const float* __restrict__ cw1, const float* __restrict__ dw1,
    const float* __restrict__ mw1, const float* __restrict__ aw1,
    unsigned short* __restrict__ w1b)
{
    int r = blockIdx.x;          // 0..1023 global K row
    int n = threadIdx.x;         // 0..255
    const float* src; int k, off;
    if (r < 256)      { src = cw1; k = r;       off = W1B_OFF0; }
    else if (r < 384) { src = dw1; k = r - 256; off = W1B_OFF1; }
    else if (r < 512) { src = mw1; k = r - 384; off = W1B_OFF2; }
    else              { src = aw1; k = r - 512; off = W1B_OFF3; }
    w1b[off + (((k >> 3) * 256 + n) << 3) + (k & 7)] = f2bf(src[k * 256 + n]);
}

// ---------------------------------------------------------------------------
// Phase 0b: gate_w -> fp64 packed per-feature-d:
//   gwd[d*16 + blk*4 + o] = (double)gw[(blk*128 + d)*4 + o],  d in [0,128)
// so the gate kernel's wave-uniform weight reads become s_load.
// ---------------------------------------------------------------------------
__global__ __launch_bounds__(256) void gconv_kernel(
    const float* __restrict__ gw, double* __restrict__ gwd)
{
    int i = blockIdx.x * 256 + threadIdx.x;    // 0..2047
    int d = i >> 4, blk = (i >> 2) & 3, o = i & 3;
    gwd[i] = (double)gw[(blk * 128 + d) * 4 + o];
}

// ---------------------------------------------------------------------------
// Phase 1: gate. Block = 256 edges, processed in 4 sub-batches of 64.
// Per sub-batch: stage 128 z-rows (64 zu + 64 zv) coalesced into LDS in two
// 64-d halves; wave w handles d-chunk [H*64+16w, +16) for ALL 64 edges
// (lane = edge) with fp64 weights via scalar loads. No cross-lane shuffles;
// the 4 wave-partials are summed through an 8 KB LDS buffer. fp64 logits ->
// identical softmax/argmax/compaction tail as the previously-passing rounds.
// ---------------------------------------------------------------------------
__global__ __launch_bounds__(256) void gate_kernel(
    const float* __restrict__ z, const int* __restrict__ u, const int* __restrict__ v,
    const double* __restrict__ gwd, const float* __restrict__ gb,
    float* __restrict__ probsum, unsigned* __restrict__ gcount,
    int* __restrict__ lists, float* __restrict__ pval)
{
    __shared__ float  zbuf[128 * 66];       // 33.8 KB, pad 66 keeps b64 aligned
    __shared__ double plog[4 * 64 * 4];     // 8 KB partial logits
    __shared__ float s_ps[4];
    __shared__ int   s_cnt[4];
    __shared__ int   s_base[4];

    int tid  = threadIdx.x;
    int lane = tid & 63;
    int wave = __builtin_amdgcn_readfirstlane(tid >> 6);

    double L[4] = {0.0, 0.0, 0.0, 0.0};     // logits of the edge this thread owns

    int r  = tid >> 1;        // staging row 0..127
    int hh = tid & 1;         // staging half-row

    for (int s = 0; s < 4; ++s) {
        int ebase = blockIdx.x * 256 + s * 64;
        int node = (r < 64) ? u[ebase + r] : v[ebase + (r - 64)];
        const float* zrow = z + (long)node * D_FEAT;

        double acc[4] = {0.0, 0.0, 0.0, 0.0};

        for (int H = 0; H < 2; ++H) {
            __syncthreads();      // zbuf safe to overwrite
            {
                const float4* src = (const float4*)(zrow + H * 64 + hh * 32);
                float* dst = zbuf + r * 66 + hh * 32;
                #pragma unroll
                for (int j = 0; j < 8; ++j) {
                    float4 t4 = src[j];
                    *(float2*)(dst + 4 * j)     = make_float2(t4.x, t4.y);
                    *(float2*)(dst + 4 * j + 2) = make_float2(t4.z, t4.w);
                }
            }
            __syncthreads();
            // compute: wave's d-chunk = [H*64 + wave*16, +16), lane = edge
            const float* zur = zbuf + lane * 66;
            const float* zvr = zbuf + (64 + lane) * 66;
            int loff = wave * 16;
            const double* W = gwd + (size_t)(H * 64 + wave * 16) * 16;
            #pragma unroll
            for (int dd = 0; dd < 16; dd += 2) {
                float2 a2 = *(const float2*)(zur + loff + dd);
                float2 b2 = *(const float2*)(zvr + loff + dd);
                const double* W0 = W + (size_t)dd * 16;
                const double* W1 = W0 + 16;
                {
                    float adf = fabsf(a2.x - b2.x);
                    float mf  = a2.x * b2.x;
                    double a = (double)a2.x, b = (double)b2.x;
                    double ad = (double)adf, m = (double)mf;
                    #pragma unroll
                    for (int o = 0; o < 4; ++o)
                        acc[o] = fma(m, W0[12 + o], fma(ad, W0[8 + o],
                                 fma(b, W0[4 + o], fma(a, W0[o], acc[o]))));
                }
                {
                    float adf = fabsf(a2.y - b2.y);
                    float mf  = a2.y * b2.y;
                    double a = (double)a2.y, b = (double)b2.y;
                    double ad = (double)adf, m = (double)mf;
                    #pragma unroll
                    for (int o = 0; o < 4; ++o)
                        acc[o] = fma(m, W1[12 + o], fma(ad, W1[8 + o],
                                 fma(b, W1[4 + o], fma(a, W1[o], acc[o]))));
                }
            }
        }
        #pragma unroll
        for (int o = 0; o < 4; ++o)
            plog[(wave * 64 + lane) * 4 + o] = acc[o];
        __syncthreads();
        if (wave == s) {
            #pragma unroll
            for (int o = 0; o < 4; ++o)
                L[o] = plog[(0 * 64 + lane) * 4 + o] + plog[(1 * 64 + lane) * 4 + o]
                     + plog[(2 * 64 + lane) * 4 + o] + plog[(3 * 64 + lane) * 4 + o];
        }
    }

    // ---- tail (unchanged from passing rounds): thread tid owns edge blk*256+tid ----
    int e = blockIdx.x * 256 + tid;

    double l0 = L[0] + (double)gb[0], l1 = L[1] + (double)gb[1];
    double l2 = L[2] + (double)gb[2], l3 = L[3] + (double)gb[3];

    double mx = fmax(fmax(l0, l1), fmax(l2, l3));
    double e0 = exp(l0 - mx), e1 = exp(l1 - mx), e2 = exp(l2 - mx), e3 = exp(l3 - mx);
    double ssum = e0 + e1 + e2 + e3;
    float p[4];
    p[0] = (float)(e0 / ssum); p[1] = (float)(e1 / ssum);
    p[2] = (float)(e2 / ssum); p[3] = (float)(e3 / ssum);

    int   sel  = 0;
    float best = p[0];
    #pragma unroll
    for (int k = 1; k < 4; ++k) {            // strict > keeps first index on ties
        if (p[k] > best) { best = p[k]; sel = k; }
    }

    if (tid < 4) { s_ps[tid] = 0.0f; s_cnt[tid] = 0; }
    __syncthreads();

    float q0 = p[0], q1 = p[1], q2 = p[2], q3 = p[3];
    #pragma unroll
    for (int off = 32; off > 0; off >>= 1) {
        q0 += __shfl_down(q0, off);
        q1 += __shfl_down(q1, off);
        q2 += __shfl_down(q2, off);
        q3 += __shfl_down(q3, off);
    }
    if (lane == 0) {
        atomicAdd(&s_ps[0], q0); atomicAdd(&s_ps[1], q1);
        atomicAdd(&s_ps[2], q2); atomicAdd(&s_ps[3], q3);
    }

    unsigned long long lt = (lane == 0) ? 0ull : ((~0ull) >> (64 - lane));
    int mywb = 0, myrank = 0;
    #pragma unroll
    for (int k = 0; k < 4; ++k) {
        unsigned long long mask = __ballot(sel == k);
        if (mask) {
            int leader = (int)__ffsll((unsigned long long)mask) - 1;
            int wb = 0;
            if (lane == leader) wb = atomicAdd(&s_cnt[k], (int)__popcll(mask));
            wb = __shfl(wb, leader);
            if (sel == k) { mywb = wb; myrank = (int)__popcll(mask & lt); }
        }
    }
    __syncthreads();

    if (tid < 4) {
        s_base[tid] = (int)atomicAdd(&gcount[tid], (unsigned)s_cnt[tid]);
        atomicAdd(&probsum[tid], s_ps[tid]);
    }
    __syncthreads();

    int pos = s_base[sel] + mywb + myrank;
    lists[sel * E_EDGES + pos] = e;
    pval[e] = best;
}

// ---------------------------------------------------------------------------
// Phase 2: selected-expert MLP. Tile = 64 edges x 256 hidden.
// Features for the whole tile are built ONCE per pass into a 32 KB bf16 LDS
// buffer (XOR-swizzled 16B groups: addr = m*Kc + ((g ^ (m&7))<<3)), then the
// K-loop runs with ZERO barriers: ds_read_b128 A-frags + register-prefetched
// B-frags + 16 MFMA per iteration. F=512 runs as two 256-wide passes.
// ---------------------------------------------------------------------------
__device__ __forceinline__ float4 feat4(int ex, const float* zu, const float* zv, int fg) {
    if (ex == 0) {
        return (fg < 128) ? *(const float4*)(zu + fg) : *(const float4*)(zv + fg - 128);
    } else if (ex == 1) {
        float4 a = *(const float4*)(zu + fg);
        float4 b = *(const float4*)(zv + fg);
        return make_float4(fabsf(a.x - b.x), fabsf(a.y - b.y), fabsf(a.z - b.z), fabsf(a.w - b.w));
    } else if (ex == 2) {
        float4 a = *(const float4*)(zu + fg);
        float4 b = *(const float4*)(zv + fg);
        return make_float4(a.x * b.x, a.y * b.y, a.z * b.z, a.w * b.w);
    } else {
        if (fg < 128) return *(const float4*)(zu + fg);
        if (fg < 256) return *(const float4*)(zv + fg - 128);
        if (fg < 384) {
            float4 a = *(const float4*)(zu + fg - 256);
            float4 b = *(const float4*)(zv + fg - 256);
            return make_float4(fabsf(a.x - b.x), fabsf(a.y - b.y), fabsf(a.z - b.z), fabsf(a.w - b.w));
        }
        float4 a = *(const float4*)(zu + fg - 384);
        float4 b = *(const float4*)(zv + fg - 384);
        return make_float4(a.x * b.x, a.y * b.y, a.z * b.z, a.w * b.w);
    }
}

__global__ __launch_bounds__(256) void expert_kernel(
    const float* __restrict__ z, const int* __restrict__ u, const int* __restrict__ v,
    const unsigned short* __restrict__ w1b,
    const float* __restrict__ cb1, const float* __restrict__ cw2, const float* __restrict__ cb2,
    const float* __restrict__ db1, const float* __restrict__ dw2, const float* __restrict__ db2,
    const float* __restrict__ mb1, const float* __restrict__ mw2, const float* __restrict__ mb2,
    const float* __restrict__ ab1, const float* __restrict__ aw2, const float* __restrict__ ab2,
    const unsigned* __restrict__ gcount, const int* __restrict__ lists,
    const float* __restrict__ pval, float* __restrict__ out)
{
    int ex = blockIdx.y;
    const float *pb1, *pw2, *pb2;
    int F, w1off;
    if (ex == 0)      { pb1 = cb1; pw2 = cw2; pb2 = cb2; F = 256; w1off = W1B_OFF0; }
    else if (ex == 1) { pb1 = db1; pw2 = dw2; pb2 = db2; F = 128; w1off = W1B_OFF1; }
    else if (ex == 2) { pb1 = mb1; pw2 = mw2; pb2 = mb2; F = 128; w1off = W1B_OFF2; }
    else              { pb1 = ab1; pw2 = aw2; pb2 = ab2; F = 512; w1off = W1B_OFF3; }

    unsigned cnt  = gcount[ex];
    unsigned tile = blockIdx.x * 64u;
    if (tile >= cnt) return;
    int nm = (int)min(64u, cnt - tile);

    __shared__ unsigned short feat[64 * 256];   // 32 KB
    __shared__ int   s_e[64], s_u[64], s_v[64];
    __shared__ float s_pv[64];
    __shared__ float red[4][64];

    int tid  = threadIdx.x;
    int wave = tid >> 6;
    int lane = tid & 63;
    int colA = lane & 15;
    int quad = lane >> 4;

    if (tid < 64) {
        int m = tid;
        int src = (m < nm) ? (int)(tile + m) : (int)tile;   // clamp tail
        int e = lists[ex * E_EDGES + src];
        s_e[m] = e; s_u[m] = u[e]; s_v[m] = v[e]; s_pv[m] = pval[e];
    }
    __syncthreads();

    int Kc    = (F < 256) ? F : 256;
    int npass = (F > 256) ? 2 : 1;
    int kiters = Kc >> 5;
    int lcnt   = Kc >> 2;

    int fm = tid >> 2;
    int qd = tid & 3;
    const float* zu = z + (long)s_u[fm] * D_FEAT;
    const float* zv = z + (long)s_v[fm] * D_FEAT;

    const short8* wB = (const short8*)(w1b + w1off);
    int nb = wave * 64 + colA;

    floatx4 acc[4][4];
    #pragma unroll
    for (int t = 0; t < 4; ++t)
        #pragma unroll
        for (int j = 0; j < 4; ++j)
            acc[t][j] = (floatx4)(0.0f);

    // prefetch B-frags for kg = 0
    short8 pf0, pf1, pf2, pf3;
    {
        int g = quad;
        pf0 = wB[g * 256 + nb];      pf1 = wB[g * 256 + nb + 16];
        pf2 = wB[g * 256 + nb + 32]; pf3 = wB[g * 256 + nb + 48];
    }

    for (int pass = 0; pass < npass; ++pass) {
        int kbase = pass << 8;
        if (pass > 0) __syncthreads();          // feat reads of prev pass done
        // ---- phase A: build 64 x Kc bf16 feature tile ----
        int lend = qd * lcnt + lcnt;
        for (int l0 = qd * lcnt; l0 < lend; l0 += 8) {
            float4 v0 = feat4(ex, zu, zv, kbase + l0);
            float4 v1 = feat4(ex, zu, zv, kbase + l0 + 4);
            short8 pk;
            pk[0] = (short)f2bf(v0.x); pk[1] = (short)f2bf(v0.y);
            pk[2] = (short)f2bf(v0.z); pk[3] = (short)f2bf(v0.w);
            pk[4] = (short)f2bf(v1.x); pk[5] = (short)f2bf(v1.y);
            pk[6] = (short)f2bf(v1.z); pk[7] = (short)f2bf(v1.w);
            int g = (l0 >> 3) ^ (fm & 7);
            *(short8*)(&feat[fm * Kc + (g << 3)]) = pk;
        }
        __syncthreads();
        // ---- K-loop: no barriers ----
        for (int it = 0; it < kiters; ++it) {
            short8 cb0f = pf0, cb1f = pf1, cb2f = pf2, cb3f = pf3;
            int kg = kbase + (it << 5);
            if (kg + 32 < F) {
                int g2 = ((kg + 32) >> 3) + quad;
                pf0 = wB[g2 * 256 + nb];      pf1 = wB[g2 * 256 + nb + 16];
                pf2 = wB[g2 * 256 + nb + 32]; pf3 = wB[g2 * 256 + nb + 48];
            }
            short8 af[4];
            #pragma unroll
            for (int t = 0; t < 4; ++t) {
                int m = colA + 16 * t;
                int g = ((it << 2) + quad) ^ (m & 7);
                af[t] = *(const short8*)(&feat[m * Kc + (g << 3)]);
            }
            #pragma unroll
            for (int t = 0; t < 4; ++t) {
                acc[t][0] = __builtin_amdgcn_mfma_f32_16x16x32_bf16(af[t], cb0f, acc[t][0], 0, 0, 0);
                acc[t][1] = __builtin_amdgcn_mfma_f32_16x16x32_bf16(af[t], cb1f, acc[t][1], 0, 0, 0);
                acc[t][2] = __builtin_amdgcn_mfma_f32_16x16x32_bf16(af[t], cb2f, acc[t][2], 0, 0, 0);
                acc[t][3] = __builtin_amdgcn_mfma_f32_16x16x32_bf16(af[t], cb3f, acc[t][3], 0, 0, 0);
            }
        }
    }

    // ---- epilogue: hidden = relu(acc + b1[h]); per-edge sum of hidden*w2[h] ----
    float b1v[4], w2v[4];
    #pragma unroll
    for (int j = 0; j < 4; ++j) {
        int h = wave * 64 + j * 16 + colA;
        b1v[j] = pb1[h];
        w2v[j] = pw2[h];
    }

    #pragma unroll
    for (int t = 0; t < 4; ++t) {
        #pragma unroll
        for (int rr = 0; rr < 4; ++rr) {
            float sacc = 0.0f;
            #pragma unroll
            for (int j = 0; j < 4; ++j) {
                float h = acc[t][j][rr] + b1v[j];
                sacc += fmaxf(h, 0.0f) * w2v[j];
            }
            sacc += __shfl_xor(sacc, 1);
            sacc += __shfl_xor(sacc, 2);
            sacc += __shfl_xor(sacc, 4);
            sacc += __shfl_xor(sacc, 8);
            if (colA == 0) {
                int m = 16 * t + quad * 4 + rr;
                red[wave][m] = sacc;
            }
        }
    }
    __syncthreads();

    if (tid < 64) {
        int m = tid;
        if (m < nm) {
            float sc = red[0][m] + red[1][m] + red[2][m] + red[3][m] + pb2[0];
            out[s_e[m]] = s_pv[m] * sc;
        }
    }
}

// ---------------------------------------------------------------------------
// Phase 3: aux loss
// ---------------------------------------------------------------------------
__global__ void aux_kernel(const float* __restrict__ probsum, float* __restrict__ out)
{
    if (threadIdx.x == 0 && blockIdx.x == 0) {
        float a = 0.0f;
        #pragma unroll
        for (int k = 0; k < 4; ++k) {
            float mean = probsum[k] * (1.0f / (float)E_EDGES);
            a += mean * mean;
        }
        out[E_EDGES] = a * (float)NEXP;
    }
}

extern "C" void kernel_launch(void* const* d_in, const int* in_sizes, int n_in,
                              void* d_out, int out_size, void* d_ws, size_t ws_size,
                              hipStream_t stream)
{
    const float* z   = (const float*)d_in[0];
    const int*   u   = (const int*)d_in[1];
    const int*   v   = (const int*)d_in[2];
    const float* gw  = (const float*)d_in[3];
    const float* gb  = (const float*)d_in[4];
    const float* cw1 = (const float*)d_in[5];
    const float* cb1 = (const float*)d_in[6];
    const float* cw2 = (const float*)d_in[7];
    const float* cb2 = (const float*)d_in[8];
    const float* dw1 = (const float*)d_in[9];
    const float* db1 = (const float*)d_in[10];
    const float* dw2 = (const float*)d_in[11];
    const float* db2 = (const float*)d_in[12];
    const float* mw1 = (const float*)d_in[13];
    const float* mb1 = (const float*)d_in[14];
    const float* mw2 = (const float*)d_in[15];
    const float* mb2 = (const float*)d_in[16];
    const float* aw1 = (const float*)d_in[17];
    const float* ab1 = (const float*)d_in[18];
    const float* aw2 = (const float*)d_in[19];
    const float* ab2 = (const float*)d_in[20];

    float* out = (float*)d_out;
    char*  ws  = (char*)d_ws;

    float*          probsum = (float*)ws;
    unsigned*       gcount  = (unsigned*)(ws + 16);
    int*            lists   = (int*)(ws + 32);
    float*          pval    = (float*)(ws + 32 + 16ll * E_EDGES);
    unsigned short* w1b     = (unsigned short*)(ws + 32 + 20ll * E_EDGES);
    double*         gwd     = (double*)(ws + 32 + 20ll * E_EDGES + 524288);

    hipMemsetAsync(d_ws, 0, 32, stream);

    conv_kernel<<<1024, 256, 0, stream>>>(cw1, dw1, mw1, aw1, w1b);
    gconv_kernel<<<8, 256, 0, stream>>>(gw, gwd);

    gate_kernel<<<E_EDGES / 256, 256, 0, stream>>>(z, u, v, gwd, gb,
                                                   probsum, gcount, lists, pval);

    aux_kernel<<<1, 64, 0, stream>>>(probsum, out);

    dim3 g2(E_EDGES / 64, 4);
    expert_kernel<<<g2, 256, 0, stream>>>(z, u, v, w1b,
                                          cb1, cw2, cb2,
                                          db1, dw2, db2,
                                          mb1, mw2, mb2,
                                          ab1, aw2, ab2,
                                          gcount, lists, pval, out);
}